// Round 1
// baseline (867.376 us; speedup 1.0000x reference)
//
#include <hip/hip_runtime.h>
#include <hip/hip_bf16.h>

// Problem constants
#define BATCH 32
#define C 160
#define H 112
#define W 112
#define HW (H * W)            // 12544
#define NT 7                  // N-tiles per row: 7*16 = 112
#define THREADS 448           // 7 waves
#define SB 168                // LDS row stride in bf16 (16B aligned, 2-way bank alias only)

typedef __bf16 bf16_t;
typedef bf16_t bf16x8 __attribute__((ext_vector_type(8)));
typedef float f32x4 __attribute__((ext_vector_type(4)));

// Workspace layout (bytes). Requires ws_size >= ~128.6 MB.
#define P_BYTES   ((size_t)BATCH * C * HW * 2)   // 128,450,560 (bf16 intermediate P)
#define WALL_OFF  (P_BYTES)                      // 16B aligned
#define WFRAG_B   (10 * 5 * 64 * 8 * 2)          // 51,200 per weight matrix
#define WFUSE_OFF (WALL_OFF + WFRAG_B)
#define BNS_OFF   (WFUSE_OFF + WFRAG_B)          // bn scale, 160 f32
#define BNB_OFF   (BNS_OFF + 160 * 4)            // bn shift, 160 f32
#define BALL_OFF  (BNB_OFF + 160 * 4)            // stacked branch bias, 160 f32

// ---------------------------------------------------------------------------
// Prep: bn scale/shift; pack W_all (branch-concat order t,b,r,l,c) and W_fuse
// into MFMA A-fragment lane order: A[m = lane&15][k = (lane>>4)*8 + j].
// frag index = ((mt*5 + ks)*64 + lane)*8 + j,  m = mt*16+(lane&15), k = ks*32+(lane>>4)*8+j
// ---------------------------------------------------------------------------
__global__ __launch_bounds__(256) void prep_kernel(
    const float* __restrict__ Wt, const float* __restrict__ Wb,
    const float* __restrict__ Wr, const float* __restrict__ Wl,
    const float* __restrict__ Wc,
    const float* __restrict__ bt, const float* __restrict__ bb,
    const float* __restrict__ br, const float* __restrict__ bl,
    const float* __restrict__ bc,
    const float* __restrict__ Wfuse,
    const float* __restrict__ gamma, const float* __restrict__ beta,
    const float* __restrict__ mean, const float* __restrict__ var,
    char* __restrict__ ws)
{
    bf16_t* wallf  = (bf16_t*)(ws + WALL_OFF);
    bf16_t* wfusef = (bf16_t*)(ws + WFUSE_OFF);
    float* bns  = (float*)(ws + BNS_OFF);
    float* bnb  = (float*)(ws + BNB_OFF);
    float* ball = (float*)(ws + BALL_OFF);

    const float* Wbr[5] = {Wt, Wb, Wr, Wl, Wc};
    const float* bbr[5] = {bt, bb, br, bl, bc};

    int tid = blockIdx.x * blockDim.x + threadIdx.x;
    int nth = gridDim.x * blockDim.x;

    for (int idx = tid; idx < 10 * 5 * 64 * 8; idx += nth) {
        int j    = idx & 7;
        int lane = (idx >> 3) & 63;
        int rest = idx >> 9;
        int ks   = rest % 5;
        int mt   = rest / 5;
        int m = mt * 16 + (lane & 15);
        int k = ks * 32 + ((lane >> 4) << 3) + j;
        wallf[idx]  = (bf16_t)Wbr[m >> 5][(m & 31) * C + k];
        wfusef[idx] = (bf16_t)Wfuse[m * C + k];
    }
    for (int c = tid; c < C; c += nth) {
        float s = gamma[c] * rsqrtf(var[c] + 1e-5f);
        bns[c]  = s;
        bnb[c]  = beta[c] - mean[c] * s;
        ball[c] = bbr[c >> 5][c & 31];
    }
}

// ---------------------------------------------------------------------------
// Stage 1: P[b, m, y, x] = sum_k W_all[m,k] * gelu(bn(x[b,k,y,x])) + b_all[m]
// One block per (b, y). B-operand staged in LDS k-contiguous per pixel.
// ---------------------------------------------------------------------------
__global__ __launch_bounds__(THREADS) void stage1_kernel(
    const float* __restrict__ x, char* __restrict__ ws)
{
    __shared__ __align__(16) bf16_t Bs[W * SB];

    const bf16_t* wallf = (const bf16_t*)(ws + WALL_OFF);
    const float* bns  = (const float*)(ws + BNS_OFF);
    const float* bnb  = (const float*)(ws + BNB_OFF);
    const float* ball = (const float*)(ws + BALL_OFF);
    bf16_t* P = (bf16_t*)ws;

    int b = blockIdx.x / H;
    int y = blockIdx.x % H;
    int tid = threadIdx.x;

    // Staging: load x row (all 160 channels), BN + exact GELU, bf16 into LDS.
    for (int i = tid; i < C * W; i += THREADS) {
        int c  = i / W;
        int px = i - c * W;
        float v = x[((size_t)(b * C + c) * H + y) * W + px];
        float h = v * bns[c] + bnb[c];
        h = 0.5f * h * (1.0f + erff(h * 0.70710678118654752f));
        Bs[px * SB + c] = (bf16_t)h;
    }
    __syncthreads();

    int wave = tid >> 6;
    int lane = tid & 63;
    int n0   = wave * 16;
    int nl   = lane & 15;
    int quad = lane >> 4;

    f32x4 acc[10];
#pragma unroll
    for (int mt = 0; mt < 10; ++mt) acc[mt] = (f32x4){0.f, 0.f, 0.f, 0.f};

#pragma unroll
    for (int ks = 0; ks < 5; ++ks) {
        bf16x8 bfrag = *(const bf16x8*)&Bs[(n0 + nl) * SB + ks * 32 + quad * 8];
#pragma unroll
        for (int mt = 0; mt < 10; ++mt) {
            bf16x8 afrag = *(const bf16x8*)&wallf[((mt * 5 + ks) * 64 + lane) * 8];
            acc[mt] = __builtin_amdgcn_mfma_f32_16x16x32_bf16(afrag, bfrag, acc[mt], 0, 0, 0);
        }
    }

    // Epilogue: C/D layout col = lane&15, row = quad*4 + r.
    size_t base = (size_t)b * C * HW + (size_t)y * W + n0 + nl;
#pragma unroll
    for (int mt = 0; mt < 10; ++mt) {
#pragma unroll
        for (int r = 0; r < 4; ++r) {
            int m = mt * 16 + quad * 4 + r;
            P[base + (size_t)m * HW] = (bf16_t)(acc[mt][r] + ball[m]);
        }
    }
}

// ---------------------------------------------------------------------------
// Stage 2: out[b, o, y, x] = b_fuse[o] + sum_k W_fuse[o,k] * Pshift[k]
// where K-block kb of P is read from the shifted pixel:
//   kb0 (t): (y+1, x)  kb1 (b): (y-1, x)  kb2 (r): (y, x-1)  kb3 (l): (y, x+1)
//   kb4 (c): (y, x);  out-of-range -> 0 (drops branch bias at borders, matching pad).
// ---------------------------------------------------------------------------
__global__ __launch_bounds__(THREADS) void stage2_kernel(
    char* __restrict__ ws, const float* __restrict__ bfuse,
    float* __restrict__ out)
{
    __shared__ __align__(16) bf16_t Bs[W * SB];

    const bf16_t* wfusef = (const bf16_t*)(ws + WFUSE_OFF);
    const bf16_t* P = (const bf16_t*)ws;

    int b = blockIdx.x / H;
    int y = blockIdx.x % H;
    int tid = threadIdx.x;

    for (int i = tid; i < C * W; i += THREADS) {
        int c  = i / W;
        int px = i - c * W;
        int kb = c >> 5;
        int sy = y, sx = px;
        bool valid = true;
        if (kb == 0)      { sy = y + 1;  valid = (sy < H);  }
        else if (kb == 1) { sy = y - 1;  valid = (sy >= 0); }
        else if (kb == 2) { sx = px - 1; valid = (sx >= 0); }
        else if (kb == 3) { sx = px + 1; valid = (sx < W);  }
        bf16_t v = (bf16_t)0.f;
        if (valid) v = P[(size_t)(b * C + c) * HW + sy * W + sx];
        Bs[px * SB + c] = v;
    }
    __syncthreads();

    int wave = tid >> 6;
    int lane = tid & 63;
    int n0   = wave * 16;
    int nl   = lane & 15;
    int quad = lane >> 4;

    f32x4 acc[10];
#pragma unroll
    for (int mt = 0; mt < 10; ++mt) acc[mt] = (f32x4){0.f, 0.f, 0.f, 0.f};

#pragma unroll
    for (int ks = 0; ks < 5; ++ks) {
        bf16x8 bfrag = *(const bf16x8*)&Bs[(n0 + nl) * SB + ks * 32 + quad * 8];
#pragma unroll
        for (int mt = 0; mt < 10; ++mt) {
            bf16x8 afrag = *(const bf16x8*)&wfusef[((mt * 5 + ks) * 64 + lane) * 8];
            acc[mt] = __builtin_amdgcn_mfma_f32_16x16x32_bf16(afrag, bfrag, acc[mt], 0, 0, 0);
        }
    }

    size_t base = (size_t)b * C * HW + (size_t)y * W + n0 + nl;
#pragma unroll
    for (int mt = 0; mt < 10; ++mt) {
#pragma unroll
        for (int r = 0; r < 4; ++r) {
            int m = mt * 16 + quad * 4 + r;
            out[base + (size_t)m * HW] = acc[mt][r] + bfuse[m];
        }
    }
}

// ---------------------------------------------------------------------------
extern "C" void kernel_launch(void* const* d_in, const int* in_sizes, int n_in,
                              void* d_out, int out_size, void* d_ws, size_t ws_size,
                              hipStream_t stream)
{
    const float* x     = (const float*)d_in[0];
    const float* gamma = (const float*)d_in[1];
    const float* beta  = (const float*)d_in[2];
    const float* mean  = (const float*)d_in[3];
    const float* var   = (const float*)d_in[4];
    const float* Wt    = (const float*)d_in[5];
    const float* bt    = (const float*)d_in[6];
    const float* Wb    = (const float*)d_in[7];
    const float* bb    = (const float*)d_in[8];
    const float* Wr    = (const float*)d_in[9];
    const float* br    = (const float*)d_in[10];
    const float* Wl    = (const float*)d_in[11];
    const float* bl    = (const float*)d_in[12];
    const float* Wc    = (const float*)d_in[13];
    const float* bc    = (const float*)d_in[14];
    const float* Wfuse = (const float*)d_in[15];
    const float* bfuse = (const float*)d_in[16];

    char* ws = (char*)d_ws;
    float* out = (float*)d_out;

    prep_kernel<<<64, 256, 0, stream>>>(Wt, Wb, Wr, Wl, Wc, bt, bb, br, bl, bc,
                                        Wfuse, gamma, beta, mean, var, ws);
    stage1_kernel<<<BATCH * H, THREADS, 0, stream>>>(x, ws);
    stage2_kernel<<<BATCH * H, THREADS, 0, stream>>>(ws, bfuse, out);
}

// Round 2
// 641.066 us; speedup vs baseline: 1.3530x; 1.3530x over previous
//
#include <hip/hip_runtime.h>
#include <hip/hip_bf16.h>

// Problem constants
#define BATCH 32
#define C 160
#define H 112
#define W 112
#define HW (H * W)            // 12544
#define NT 7                  // N-tiles per row: 7*16 = 112

typedef __bf16 bf16_t;
typedef bf16_t bf16x8 __attribute__((ext_vector_type(8)));
typedef float f32x4 __attribute__((ext_vector_type(4)));

// Workspace layout (bytes).
// P is stored as [b][kb(5)][y][x][32ch] bf16, channels within a 32-block in the
// PERMUTED order pos = quad*8+jj  <->  chan = (jj<4) ? quad*4+jj : 16+quad*4+(jj-4)
// so stage2 B-fragments are single dwordx4 loads and stage1 epilogue stores are
// single dwordx4 stores (both 1KB/wave/instr, fully coalesced).
#define P_BYTES   ((size_t)BATCH * C * HW * 2)   // 128,450,560
#define WALL_OFF  (P_BYTES)
#define WFRAG_B   (10 * 5 * 64 * 8 * 2)          // 51,200 per weight matrix
#define WFUSE_OFF (WALL_OFF + WFRAG_B)
#define BN2_OFF   (WFUSE_OFF + WFRAG_B)          // float2 {scale, shift} per channel
#define BALL_OFF  (BN2_OFF + C * 8)              // stacked branch bias, 160 f32

// ---------------------------------------------------------------------------
// Prep: bn scale/shift; pack W_all (natural k order) and W_fuse (permuted k
// order matching P's in-block channel permutation) into MFMA A-fragment order:
// frag idx = ((mt*5 + ks)*64 + lane)*8 + j, m = mt*16 + (lane&15).
// ---------------------------------------------------------------------------
__global__ __launch_bounds__(256) void prep_kernel(
    const float* __restrict__ Wt, const float* __restrict__ Wb,
    const float* __restrict__ Wr, const float* __restrict__ Wl,
    const float* __restrict__ Wc,
    const float* __restrict__ bt, const float* __restrict__ bb,
    const float* __restrict__ br, const float* __restrict__ bl,
    const float* __restrict__ bc,
    const float* __restrict__ Wfuse,
    const float* __restrict__ gamma, const float* __restrict__ beta,
    const float* __restrict__ mean, const float* __restrict__ var,
    char* __restrict__ ws)
{
    bf16_t* wallf  = (bf16_t*)(ws + WALL_OFF);
    bf16_t* wfusef = (bf16_t*)(ws + WFUSE_OFF);
    float2* bn2 = (float2*)(ws + BN2_OFF);
    float*  ball = (float*)(ws + BALL_OFF);

    const float* Wbr[5] = {Wt, Wb, Wr, Wl, Wc};
    const float* bbr[5] = {bt, bb, br, bl, bc};

    int tid = blockIdx.x * blockDim.x + threadIdx.x;
    int nth = gridDim.x * blockDim.x;

    for (int idx = tid; idx < 10 * 5 * 64 * 8; idx += nth) {
        int j    = idx & 7;
        int lane = (idx >> 3) & 63;
        int rest = idx >> 9;
        int ks   = rest % 5;
        int mt   = rest / 5;
        int m  = mt * 16 + (lane & 15);
        int q  = lane >> 4;
        // W_all: natural k order (stage1 loads x directly by channel)
        int k_nat = ks * 32 + q * 8 + j;
        wallf[idx] = (bf16_t)Wbr[m >> 5][(m & 31) * C + k_nat];
        // W_fuse: permuted k order matching P's in-block channel layout
        int chan32 = (j < 4) ? (q * 4 + j) : (16 + q * 4 + (j - 4));
        wfusef[idx] = (bf16_t)Wfuse[m * C + ks * 32 + chan32];
    }
    for (int c = tid; c < C; c += nth) {
        float s = gamma[c] * rsqrtf(var[c] + 1e-5f);
        bn2[c] = make_float2(s, beta[c] - mean[c] * s);
        ball[c] = bbr[c >> 5][c & 31];
    }
}

// ---------------------------------------------------------------------------
// Stage 1: P = W_all @ gelu(bn(x)) + b_all, P in permuted [b][kb][y][x][32] bf16.
// One wave per (b, y, 16-px tile). No LDS: x loaded straight into B-fragments.
// ---------------------------------------------------------------------------
__global__ __launch_bounds__(256) void stage1_kernel(
    const float* __restrict__ x, char* __restrict__ ws)
{
    const bf16_t* __restrict__ wallf = (const bf16_t*)(ws + WALL_OFF);
    const float2* __restrict__ bn2 = (const float2*)(ws + BN2_OFF);
    const float*  __restrict__ ball = (const float*)(ws + BALL_OFF);
    bf16_t* __restrict__ P = (bf16_t*)ws;

    int wid  = blockIdx.x * 4 + (threadIdx.x >> 6);
    int lane = threadIdx.x & 63;
    int b   = wid / (NT * H);
    int rem = wid - b * (NT * H);
    int y   = rem / NT;
    int t   = rem - y * NT;
    int nl = lane & 15, quad = lane >> 4;
    int px = t * 16 + nl;

    f32x4 acc[10];
#pragma unroll
    for (int mt = 0; mt < 10; ++mt)
        acc[mt] = *(const f32x4*)&ball[mt * 16 + quad * 4];

    const float* xp = x + (size_t)b * C * HW + (size_t)y * W + px;

#pragma unroll
    for (int ks = 0; ks < 5; ++ks) {
        float v[8];
#pragma unroll
        for (int j = 0; j < 8; ++j)
            v[j] = xp[(size_t)(ks * 32 + quad * 8 + j) * HW];
        bf16x8 bfrag;
#pragma unroll
        for (int j = 0; j < 8; ++j) {
            int c = ks * 32 + quad * 8 + j;
            float2 sb = bn2[c];
            float h = v[j] * sb.x + sb.y;
            h = 0.5f * h * (1.0f + erff(h * 0.70710678118654752f));
            bfrag[j] = (bf16_t)h;
        }
#pragma unroll
        for (int mt = 0; mt < 10; ++mt) {
            bf16x8 afrag = *(const bf16x8*)&wallf[((mt * 5 + ks) * 64 + lane) * 8];
            acc[mt] = __builtin_amdgcn_mfma_f32_16x16x32_bf16(afrag, bfrag, acc[mt], 0, 0, 0);
        }
    }

    // Epilogue: pack (acc[2kb], acc[2kb+1]) -> permuted 32-block, one 16B store per kb.
    size_t pb = (((size_t)(b * 5) * H + y) * W + px) * 32 + quad * 8;
#pragma unroll
    for (int kb = 0; kb < 5; ++kb) {
        bf16x8 o;
#pragma unroll
        for (int r = 0; r < 4; ++r) {
            o[r]     = (bf16_t)acc[kb * 2][r];       // chan kb*32 + quad*4 + r
            o[r + 4] = (bf16_t)acc[kb * 2 + 1][r];   // chan kb*32 + 16 + quad*4 + r
        }
        *(bf16x8*)&P[pb + (size_t)kb * HW * 32] = o;
    }
}

// ---------------------------------------------------------------------------
// Stage 2: out = W_fuse @ shift(P) + b_fuse. Shifts folded into P base address:
//   kb0 (t): (y+1,x)  kb1 (b): (y-1,x)  kb2 (r): (y,x-1)  kb3 (l): (y,x+1)  kb4: (y,x)
// Out-of-range -> zero fragment (drops branch bias at borders, matching pad).
// All shifted addresses are provably within the P region; masking is in-register.
// ---------------------------------------------------------------------------
__global__ __launch_bounds__(256) void stage2_kernel(
    char* __restrict__ ws, const float* __restrict__ bfuse,
    float* __restrict__ out)
{
    const bf16_t* __restrict__ wfusef = (const bf16_t*)(ws + WFUSE_OFF);
    const bf16_t* __restrict__ P = (const bf16_t*)ws;

    int wid  = blockIdx.x * 4 + (threadIdx.x >> 6);
    int lane = threadIdx.x & 63;
    int b   = wid / (NT * H);
    int rem = wid - b * (NT * H);
    int y   = rem / NT;
    int t   = rem - y * NT;
    int nl = lane & 15, quad = lane >> 4;
    int px = t * 16 + nl;

    f32x4 acc[10];
#pragma unroll
    for (int mt = 0; mt < 10; ++mt)
        acc[mt] = *(const f32x4*)&bfuse[mt * 16 + quad * 4];

    bf16x8 zero;
#pragma unroll
    for (int j = 0; j < 8; ++j) zero[j] = (bf16_t)0.0f;

    auto ldP = [&](int kb, int yy, int xx) -> bf16x8 {
        return *(const bf16x8*)&P[(((size_t)(b * 5 + kb) * H + yy) * W + xx) * 32 + quad * 8];
    };

    bf16x8 f[5];
    f[0] = ldP(0, y + 1, px); if (y + 1 >= H) f[0] = zero;
    f[1] = ldP(1, y - 1, px); if (y == 0)     f[1] = zero;
    f[2] = ldP(2, y, px - 1); if (px == 0)    f[2] = zero;
    f[3] = ldP(3, y, px + 1); if (px == W - 1) f[3] = zero;
    f[4] = ldP(4, y, px);

#pragma unroll
    for (int ks = 0; ks < 5; ++ks) {
#pragma unroll
        for (int mt = 0; mt < 10; ++mt) {
            bf16x8 afrag = *(const bf16x8*)&wfusef[((mt * 5 + ks) * 64 + lane) * 8];
            acc[mt] = __builtin_amdgcn_mfma_f32_16x16x32_bf16(afrag, f[ks], acc[mt], 0, 0, 0);
        }
    }

    size_t ob = (size_t)b * C * HW + (size_t)y * W + px;
#pragma unroll
    for (int mt = 0; mt < 10; ++mt) {
#pragma unroll
        for (int r = 0; r < 4; ++r) {
            int m = mt * 16 + quad * 4 + r;
            out[ob + (size_t)m * HW] = acc[mt][r];
        }
    }
}

// ---------------------------------------------------------------------------
extern "C" void kernel_launch(void* const* d_in, const int* in_sizes, int n_in,
                              void* d_out, int out_size, void* d_ws, size_t ws_size,
                              hipStream_t stream)
{
    const float* x     = (const float*)d_in[0];
    const float* gamma = (const float*)d_in[1];
    const float* beta  = (const float*)d_in[2];
    const float* mean  = (const float*)d_in[3];
    const float* var   = (const float*)d_in[4];
    const float* Wt    = (const float*)d_in[5];
    const float* bt    = (const float*)d_in[6];
    const float* Wb    = (const float*)d_in[7];
    const float* bb    = (const float*)d_in[8];
    const float* Wr    = (const float*)d_in[9];
    const float* br    = (const float*)d_in[10];
    const float* Wl    = (const float*)d_in[11];
    const float* bl    = (const float*)d_in[12];
    const float* Wc    = (const float*)d_in[13];
    const float* bc    = (const float*)d_in[14];
    const float* Wfuse = (const float*)d_in[15];
    const float* bfuse = (const float*)d_in[16];

    char* ws = (char*)d_ws;
    float* out = (float*)d_out;

    prep_kernel<<<64, 256, 0, stream>>>(Wt, Wb, Wr, Wl, Wc, bt, bb, br, bl, bc,
                                        Wfuse, gamma, beta, mean, var, ws);

    int nblocks = (BATCH * H * NT) / 4;   // 25088 waves / 4 waves per block
    stage1_kernel<<<nblocks, 256, 0, stream>>>(x, ws);
    stage2_kernel<<<nblocks, 256, 0, stream>>>(ws, bfuse, out);
}